// Round 8
// baseline (116.688 us; speedup 1.0000x reference)
//
#include <hip/hip_runtime.h>
#include <hip/hip_bf16.h>

#define NDIM 256
#define NN (NDIM*NDIM)

typedef __attribute__((ext_vector_type(8))) short s8bf;     // 8 x bf16 (4 VGPRs)
typedef __attribute__((ext_vector_type(4))) float f32x4;    // native float4
typedef __attribute__((ext_vector_type(16))) float f32x16;  // 32x32 MFMA accum

__device__ __forceinline__ unsigned short f2bf(float f) {
    union { float f; unsigned u; } v; v.f = f;
    unsigned u = v.u;
    return (unsigned short)((u + 0x7FFFu + ((u >> 16) & 1u)) >> 16);  // RNE
}
__device__ __forceinline__ short f2bfs(float f) {           // compiler emits v_cvt_pk_bf16_f32
    __hip_bfloat16 h = __float2bfloat16(f);
    union { __hip_bfloat16 h; short s; } v; v.h = h;
    return v.s;
}

// ---------------- expm pipeline: U = B0 + M3*(B1 + M3/720) ----------------
// M = H1 - i*H0. deg-6 Taylor; truncation ~1e-4 << bf16 noise.
// 1024 thr (16,16,4): K split 4 ways across tz + 2-way sub-accumulators.
__global__ __launch_bounds__(1024) void kmm(
    const float* __restrict__ H, float2* __restrict__ M2c, float2* __restrict__ M3c,
    unsigned short* __restrict__ Ut, int mode) {
    __shared__ float2 As[16][257];
    __shared__ float2 Bs[256][17];
    __shared__ float2 Rs[3][16][17];
    const int tx = threadIdx.x, ty = threadIdx.y, tz = threadIdx.z;
    const int tid = (tz * 16 + ty) * 16 + tx;
    const int r0 = blockIdx.y * 16, c0 = blockIdx.x * 16;

#pragma unroll
    for (int i = 0; i < 4; ++i) {               // A panel: 16 rows x 256 k
        int idx = i * 1024 + tid;
        int r = idx >> 8, k = idx & 255;
        float2 a;
        if (mode == 0)      { a.x = H[NN + (r0+r)*NDIM + k]; a.y = -H[(r0+r)*NDIM + k]; }
        else if (mode == 1) a = M2c[(r0+r)*NDIM + k];
        else                a = M3c[(r0+r)*NDIM + k];
        As[r][k] = a;
    }
#pragma unroll
    for (int i = 0; i < 4; ++i) {               // B panel: 256 k x 16 cols
        int idx = i * 1024 + tid;
        int k = idx >> 4, cc = idx & 15;
        float2 b;
        if (mode <= 1) { b.x = H[NN + k*NDIM + c0+cc]; b.y = -H[k*NDIM + c0+cc]; }
        else {
            int g = k * NDIM + c0 + cc;
            float mr = H[NN + g], mi = -H[g];
            float2 m2 = M2c[g], m3 = M3c[g];
            float di = (k == c0 + cc) ? 1.f : 0.f;
            b.x = di*(1.f/6.f) + mr*(1.f/24.f) + m2.x*(1.f/120.f) + m3.x*(1.f/720.f);
            b.y =                mi*(1.f/24.f) + m2.y*(1.f/120.f) + m3.y*(1.f/720.f);
        }
        Bs[k][cc] = b;
    }
    __syncthreads();

    float sr0=0.f, si0=0.f, sr1=0.f, si1=0.f;
#pragma unroll 8
    for (int k = tz*64; k < tz*64 + 64; k += 2) {
        float2 a = As[ty][k], b = Bs[k][tx];
        sr0 = fmaf(a.x, b.x, sr0); sr0 = fmaf(-a.y, b.y, sr0);
        si0 = fmaf(a.x, b.y, si0); si0 = fmaf(a.y, b.x, si0);
        float2 a1 = As[ty][k+1], b1 = Bs[k+1][tx];
        sr1 = fmaf(a1.x, b1.x, sr1); sr1 = fmaf(-a1.y, b1.y, sr1);
        si1 = fmaf(a1.x, b1.y, si1); si1 = fmaf(a1.y, b1.x, si1);
    }
    float sr = sr0 + sr1, si = si0 + si1;
    if (tz > 0) Rs[tz-1][ty][tx] = make_float2(sr, si);
    __syncthreads();
    if (tz == 0) {
        sr += Rs[0][ty][tx].x + Rs[1][ty][tx].x + Rs[2][ty][tx].x;
        si += Rs[0][ty][tx].y + Rs[1][ty][tx].y + Rs[2][ty][tx].y;
        int d = r0 + ty, e = c0 + tx;
        if (mode == 0)      M2c[d*NDIM + e] = make_float2(sr, si);
        else if (mode == 1) M3c[d*NDIM + e] = make_float2(sr, si);
        else {
            int g = d * NDIM + e;
            float ur = sr + ((d == e) ? 1.f : 0.f) + H[NN + g] + M2c[g].x * 0.5f;
            Ut[e * NDIM + d] = f2bf(ur);         // transposed: Ut[col][k]
        }
    }
}

// ---------------- main GEMM: out[131072 x 256] = psi @ Re(U) ----------------
// ZERO-LDS design, mfma_f32_32x32x16_bf16. 512 thr = 8 waves: 4 col-groups
// (64 cols each, B held in 128 VGPRs, loaded once from L2-hot Ut) x 2
// row-groups x 4 strips of 32 rows (256 rows/block, grid 512). A (psi)
// streamed via flat 64-step pipeline, 4-deep ring (8 KB/wave in flight).
// C-layout (m74/m101): col=lane&31, row=(reg&3)+8(reg>>2)+4(lane>>5) -> one
// 4B/lane store = 2 FULL 128B lines: direct reg->global NT stores, no LDS
// transpose, no barriers, no bank conflicts, no partial-line RMW.
__global__ __launch_bounds__(512, 2) void kgemm(
    const float* __restrict__ psi, const unsigned short* __restrict__ Ut,
    float* __restrict__ out) {
    const int t = threadIdx.x;
    const int w = t >> 6, l = t & 63;
    const int lr = l & 31, half = l >> 5;
    const int cg = w & 3, rg = w >> 2;
    const int colb = cg * 64;

    // B fragments: b[nt][ks], lane holds B[k=ks*16+half*8+j][col=colb+nt*32+lr]
    // = Ut[col*256 + k...] -> 16B contiguous loads, L2-hot (128 KB total).
    s8bf b0[16], b1[16];
#pragma unroll
    for (int ks = 0; ks < 16; ++ks) {
        b0[ks] = *(const s8bf*)(&Ut[(colb +      lr) * NDIM + ks * 16 + half * 8]);
        b1[ks] = *(const s8bf*)(&Ut[(colb + 32 + lr) * NDIM + ks * 16 + half * 8]);
    }

    const f32x4* psi4 = (const f32x4*)psi;
    const size_t rowL = (size_t)blockIdx.x * 256 + rg * 128 + lr;  // lane row, strip 0

    f32x4 ring[4][2];                            // 4-deep k-step pipeline
#pragma unroll
    for (int p = 0; p < 4; ++p) {
        size_t ad = (rowL + (size_t)(p >> 4) * 32) * 64 + (p & 15) * 4 + half * 2;
        ring[p][0] = psi4[ad]; ring[p][1] = psi4[ad + 1];
    }

    f32x16 acc0 = (f32x16)0.f, acc1 = (f32x16)0.f;

#pragma unroll
    for (int p = 0; p < 64; ++p) {               // p = strip*16 + ks
        const int ks = p & 15, strip = p >> 4;
        s8bf a;                                  // A: row=lr, k=ks*16+half*8+j
#pragma unroll
        for (int j = 0; j < 4; ++j) {
            a[j]     = f2bfs(ring[p & 3][0][j]);
            a[j + 4] = f2bfs(ring[p & 3][1][j]);
        }
        if (p + 4 < 64) {                        // refill ring slot for p+4
            const int pn = p + 4;
            size_t ad = (rowL + (size_t)(pn >> 4) * 32) * 64 + (pn & 15) * 4 + half * 2;
            ring[p & 3][0] = psi4[ad]; ring[p & 3][1] = psi4[ad + 1];
        }
        acc0 = __builtin_amdgcn_mfma_f32_32x32x16_bf16(a, b0[ks], acc0, 0, 0, 0);
        acc1 = __builtin_amdgcn_mfma_f32_32x32x16_bf16(a, b1[ks], acc1, 0, 0, 0);

        if (ks == 15) {                          // strip done: direct reg stores
            const size_t r0 = (size_t)blockIdx.x * 256 + rg * 128 + strip * 32;
#pragma unroll
            for (int r = 0; r < 16; ++r) {
                size_t row = r0 + (r & 3) + 8 * (r >> 2) + 4 * half;
                __builtin_nontemporal_store(acc0[r], &out[row * NDIM + colb + lr]);
                __builtin_nontemporal_store(acc1[r], &out[row * NDIM + colb + 32 + lr]);
            }
            acc0 = (f32x16)0.f; acc1 = (f32x16)0.f;
        }
    }
}

extern "C" void kernel_launch(void* const* d_in, const int* in_sizes, int n_in,
                              void* d_out, int out_size, void* d_ws, size_t ws_size,
                              hipStream_t stream) {
    const float* psi = (const float*)d_in[0];   // [8,4096,4,256] f32
    const float* H   = (const float*)d_in[1];   // [4,256,256]    f32
    float* out = (float*)d_out;                 // [8,4096,4,256] f32

    float2* M2c = (float2*)d_ws;                // NN complex
    float2* M3c = M2c + NN;                     // NN complex
    unsigned short* Ut = (unsigned short*)(M3c + NN);  // NN bf16 (Ut[col][k])

    dim3 cb(16, 16, 4), cg(16, 16);
    kmm<<<cg, cb, 0, stream>>>(H, M2c, M3c, Ut, 0);   // M2 = M*M
    kmm<<<cg, cb, 0, stream>>>(H, M2c, M3c, Ut, 1);   // M3 = M2*M
    kmm<<<cg, cb, 0, stream>>>(H, M2c, M3c, Ut, 2);   // Ut = bf16(Re(U))^T
    kgemm<<<512, 512, 0, stream>>>(psi, Ut, out);
}

// Round 9
// 116.504 us; speedup vs baseline: 1.0016x; 1.0016x over previous
//
#include <hip/hip_runtime.h>
#include <hip/hip_bf16.h>

#define NDIM 256
#define NN (NDIM*NDIM)

typedef __attribute__((ext_vector_type(8))) short s8bf;     // 8 x bf16 (4 VGPRs)
typedef __attribute__((ext_vector_type(4))) float f32x4;    // native float4
typedef __attribute__((ext_vector_type(16))) float f32x16;  // 32x32 MFMA accum

__device__ __forceinline__ unsigned short f2bf(float f) {
    union { float f; unsigned u; } v; v.f = f;
    unsigned u = v.u;
    return (unsigned short)((u + 0x7FFFu + ((u >> 16) & 1u)) >> 16);  // RNE
}
__device__ __forceinline__ short f2bfs(float f) {           // compiler emits v_cvt_pk_bf16_f32
    __hip_bfloat16 h = __float2bfloat16(f);
    union { __hip_bfloat16 h; short s; } v; v.h = h;
    return v.s;
}

// ---------------- expm pipeline: U = B0 + M3*(B1 + M3/720) ----------------
// M = H1 - i*H0. deg-6 Taylor; truncation ~1e-4 << bf16 noise.
// 1024 thr (16,16,4): K split 4 ways across tz + 2-way sub-accumulators.
__global__ __launch_bounds__(1024) void kmm(
    const float* __restrict__ H, float2* __restrict__ M2c, float2* __restrict__ M3c,
    unsigned short* __restrict__ Ut, int mode) {
    __shared__ float2 As[16][257];
    __shared__ float2 Bs[256][17];
    __shared__ float2 Rs[3][16][17];
    const int tx = threadIdx.x, ty = threadIdx.y, tz = threadIdx.z;
    const int tid = (tz * 16 + ty) * 16 + tx;
    const int r0 = blockIdx.y * 16, c0 = blockIdx.x * 16;

#pragma unroll
    for (int i = 0; i < 4; ++i) {               // A panel: 16 rows x 256 k
        int idx = i * 1024 + tid;
        int r = idx >> 8, k = idx & 255;
        float2 a;
        if (mode == 0)      { a.x = H[NN + (r0+r)*NDIM + k]; a.y = -H[(r0+r)*NDIM + k]; }
        else if (mode == 1) a = M2c[(r0+r)*NDIM + k];
        else                a = M3c[(r0+r)*NDIM + k];
        As[r][k] = a;
    }
#pragma unroll
    for (int i = 0; i < 4; ++i) {               // B panel: 256 k x 16 cols
        int idx = i * 1024 + tid;
        int k = idx >> 4, cc = idx & 15;
        float2 b;
        if (mode <= 1) { b.x = H[NN + k*NDIM + c0+cc]; b.y = -H[k*NDIM + c0+cc]; }
        else {
            int g = k * NDIM + c0 + cc;
            float mr = H[NN + g], mi = -H[g];
            float2 m2 = M2c[g], m3 = M3c[g];
            float di = (k == c0 + cc) ? 1.f : 0.f;
            b.x = di*(1.f/6.f) + mr*(1.f/24.f) + m2.x*(1.f/120.f) + m3.x*(1.f/720.f);
            b.y =                mi*(1.f/24.f) + m2.y*(1.f/120.f) + m3.y*(1.f/720.f);
        }
        Bs[k][cc] = b;
    }
    __syncthreads();

    float sr0=0.f, si0=0.f, sr1=0.f, si1=0.f;
#pragma unroll 8
    for (int k = tz*64; k < tz*64 + 64; k += 2) {
        float2 a = As[ty][k], b = Bs[k][tx];
        sr0 = fmaf(a.x, b.x, sr0); sr0 = fmaf(-a.y, b.y, sr0);
        si0 = fmaf(a.x, b.y, si0); si0 = fmaf(a.y, b.x, si0);
        float2 a1 = As[ty][k+1], b1 = Bs[k+1][tx];
        sr1 = fmaf(a1.x, b1.x, sr1); sr1 = fmaf(-a1.y, b1.y, sr1);
        si1 = fmaf(a1.x, b1.y, si1); si1 = fmaf(a1.y, b1.x, si1);
    }
    float sr = sr0 + sr1, si = si0 + si1;
    if (tz > 0) Rs[tz-1][ty][tx] = make_float2(sr, si);
    __syncthreads();
    if (tz == 0) {
        sr += Rs[0][ty][tx].x + Rs[1][ty][tx].x + Rs[2][ty][tx].x;
        si += Rs[0][ty][tx].y + Rs[1][ty][tx].y + Rs[2][ty][tx].y;
        int d = r0 + ty, e = c0 + tx;
        if (mode == 0)      M2c[d*NDIM + e] = make_float2(sr, si);
        else if (mode == 1) M3c[d*NDIM + e] = make_float2(sr, si);
        else {
            int g = d * NDIM + e;
            float ur = sr + ((d == e) ? 1.f : 0.f) + H[NN + g] + M2c[g].x * 0.5f;
            Ut[e * NDIM + d] = f2bf(ur);         // transposed: Ut[col][k]
        }
    }
}

// ---------------- main GEMM: out[131072 x 256] = psi @ Re(U) ----------------
// ZERO-LDS design, mfma_f32_32x32x16_bf16. 512 thr = 8 waves: 4 col-groups
// (64 cols each, B held in 128 VGPRs, loaded once from L2-hot Ut) x 2
// row-groups x 4 strips of 32 rows (256 rows/block, grid 512). A (psi)
// streamed via flat 64-step pipeline, 4-deep ring (8 KB/wave in flight).
// C-layout (m74/m101): col=lane&31, row=(reg&3)+8(reg>>2)+4(lane>>5) -> one
// 4B/lane store = 2 FULL 128B lines: direct reg->global NT stores, no LDS,
// no barriers, no bank conflicts, no partial-line RMW.
// launch_bounds(512,1): 256-VGPR cap — live state ~210 VGPR; the round-8
// (512,2)=128-cap version spilled B-frags to scratch (VGPR_Count==128,
// WRITE +20 MB, FETCH +14 MB) and was never a fair test of this design.
__global__ __launch_bounds__(512, 1) void kgemm(
    const float* __restrict__ psi, const unsigned short* __restrict__ Ut,
    float* __restrict__ out) {
    const int t = threadIdx.x;
    const int w = t >> 6, l = t & 63;
    const int lr = l & 31, half = l >> 5;
    const int cg = w & 3, rg = w >> 2;
    const int colb = cg * 64;

    // B fragments: b[nt][ks], lane holds B[k=ks*16+half*8+j][col=colb+nt*32+lr]
    // = Ut[col*256 + k...] -> 16B contiguous loads, L2-hot (128 KB total).
    s8bf b0[16], b1[16];
#pragma unroll
    for (int ks = 0; ks < 16; ++ks) {
        b0[ks] = *(const s8bf*)(&Ut[(colb +      lr) * NDIM + ks * 16 + half * 8]);
        b1[ks] = *(const s8bf*)(&Ut[(colb + 32 + lr) * NDIM + ks * 16 + half * 8]);
    }

    const f32x4* psi4 = (const f32x4*)psi;
    const size_t rowL = (size_t)blockIdx.x * 256 + rg * 128 + lr;  // lane row, strip 0

    f32x4 ring[4][2];                            // 4-deep k-step pipeline
#pragma unroll
    for (int p = 0; p < 4; ++p) {
        size_t ad = (rowL + (size_t)(p >> 4) * 32) * 64 + (p & 15) * 4 + half * 2;
        ring[p][0] = psi4[ad]; ring[p][1] = psi4[ad + 1];
    }

    f32x16 acc0 = (f32x16)0.f, acc1 = (f32x16)0.f;

#pragma unroll
    for (int p = 0; p < 64; ++p) {               // p = strip*16 + ks
        const int ks = p & 15, strip = p >> 4;
        s8bf a;                                  // A: row=lr, k=ks*16+half*8+j
#pragma unroll
        for (int j = 0; j < 4; ++j) {
            a[j]     = f2bfs(ring[p & 3][0][j]);
            a[j + 4] = f2bfs(ring[p & 3][1][j]);
        }
        if (p + 4 < 64) {                        // refill ring slot for p+4
            const int pn = p + 4;
            size_t ad = (rowL + (size_t)(pn >> 4) * 32) * 64 + (pn & 15) * 4 + half * 2;
            ring[p & 3][0] = psi4[ad]; ring[p & 3][1] = psi4[ad + 1];
        }
        acc0 = __builtin_amdgcn_mfma_f32_32x32x16_bf16(a, b0[ks], acc0, 0, 0, 0);
        acc1 = __builtin_amdgcn_mfma_f32_32x32x16_bf16(a, b1[ks], acc1, 0, 0, 0);

        if (ks == 15) {                          // strip done: direct reg stores
            const size_t r0 = (size_t)blockIdx.x * 256 + rg * 128 + strip * 32;
#pragma unroll
            for (int r = 0; r < 16; ++r) {
                size_t row = r0 + (r & 3) + 8 * (r >> 2) + 4 * half;
                __builtin_nontemporal_store(acc0[r], &out[row * NDIM + colb + lr]);
                __builtin_nontemporal_store(acc1[r], &out[row * NDIM + colb + 32 + lr]);
            }
            acc0 = (f32x16)0.f; acc1 = (f32x16)0.f;
        }
    }
}

extern "C" void kernel_launch(void* const* d_in, const int* in_sizes, int n_in,
                              void* d_out, int out_size, void* d_ws, size_t ws_size,
                              hipStream_t stream) {
    const float* psi = (const float*)d_in[0];   // [8,4096,4,256] f32
    const float* H   = (const float*)d_in[1];   // [4,256,256]    f32
    float* out = (float*)d_out;                 // [8,4096,4,256] f32

    float2* M2c = (float2*)d_ws;                // NN complex
    float2* M3c = M2c + NN;                     // NN complex
    unsigned short* Ut = (unsigned short*)(M3c + NN);  // NN bf16 (Ut[col][k])

    dim3 cb(16, 16, 4), cg(16, 16);
    kmm<<<cg, cb, 0, stream>>>(H, M2c, M3c, Ut, 0);   // M2 = M*M
    kmm<<<cg, cb, 0, stream>>>(H, M2c, M3c, Ut, 1);   // M3 = M2*M
    kmm<<<cg, cb, 0, stream>>>(H, M2c, M3c, Ut, 2);   // Ut = bf16(Re(U))^T
    kgemm<<<512, 512, 0, stream>>>(psi, Ut, out);
}

// Round 10
// 90.083 us; speedup vs baseline: 1.2953x; 1.2933x over previous
//
#include <hip/hip_runtime.h>
#include <hip/hip_bf16.h>

#define NDIM 256
#define NN (NDIM*NDIM)

typedef __attribute__((ext_vector_type(8))) short s8bf;     // 8 x bf16 (4 VGPRs)
typedef __attribute__((ext_vector_type(4))) float f32x4;    // native float4
typedef __attribute__((ext_vector_type(16))) float f32x16;  // 32x32 MFMA accum

__device__ __forceinline__ unsigned short f2bf(float f) {
    union { float f; unsigned u; } v; v.f = f;
    unsigned u = v.u;
    return (unsigned short)((u + 0x7FFFu + ((u >> 16) & 1u)) >> 16);  // RNE
}
__device__ __forceinline__ short f2bfs(float f) {           // compiler emits v_cvt_pk_bf16_f32
    __hip_bfloat16 h = __float2bfloat16(f);
    union { __hip_bfloat16 h; short s; } v; v.h = h;
    return v.s;
}

// ---------------- expm pipeline: U = B0 + M3*(B1 + M3/720) ----------------
// M = H1 - i*H0. deg-6 Taylor; truncation ~1e-4 << bf16 noise.
// 1024 thr (16,16,4): K split 4 ways across tz + 2-way sub-accumulators.
__global__ __launch_bounds__(1024) void kmm(
    const float* __restrict__ H, float2* __restrict__ M2c, float2* __restrict__ M3c,
    unsigned short* __restrict__ Ut, int mode) {
    __shared__ float2 As[16][257];
    __shared__ float2 Bs[256][17];
    __shared__ float2 Rs[3][16][17];
    const int tx = threadIdx.x, ty = threadIdx.y, tz = threadIdx.z;
    const int tid = (tz * 16 + ty) * 16 + tx;
    const int r0 = blockIdx.y * 16, c0 = blockIdx.x * 16;

#pragma unroll
    for (int i = 0; i < 4; ++i) {               // A panel: 16 rows x 256 k
        int idx = i * 1024 + tid;
        int r = idx >> 8, k = idx & 255;
        float2 a;
        if (mode == 0)      { a.x = H[NN + (r0+r)*NDIM + k]; a.y = -H[(r0+r)*NDIM + k]; }
        else if (mode == 1) a = M2c[(r0+r)*NDIM + k];
        else                a = M3c[(r0+r)*NDIM + k];
        As[r][k] = a;
    }
#pragma unroll
    for (int i = 0; i < 4; ++i) {               // B panel: 256 k x 16 cols
        int idx = i * 1024 + tid;
        int k = idx >> 4, cc = idx & 15;
        float2 b;
        if (mode <= 1) { b.x = H[NN + k*NDIM + c0+cc]; b.y = -H[k*NDIM + c0+cc]; }
        else {
            int g = k * NDIM + c0 + cc;
            float mr = H[NN + g], mi = -H[g];
            float2 m2 = M2c[g], m3 = M3c[g];
            float di = (k == c0 + cc) ? 1.f : 0.f;
            b.x = di*(1.f/6.f) + mr*(1.f/24.f) + m2.x*(1.f/120.f) + m3.x*(1.f/720.f);
            b.y =                mi*(1.f/24.f) + m2.y*(1.f/120.f) + m3.y*(1.f/720.f);
        }
        Bs[k][cc] = b;
    }
    __syncthreads();

    float sr0=0.f, si0=0.f, sr1=0.f, si1=0.f;
#pragma unroll 8
    for (int k = tz*64; k < tz*64 + 64; k += 2) {
        float2 a = As[ty][k], b = Bs[k][tx];
        sr0 = fmaf(a.x, b.x, sr0); sr0 = fmaf(-a.y, b.y, sr0);
        si0 = fmaf(a.x, b.y, si0); si0 = fmaf(a.y, b.x, si0);
        float2 a1 = As[ty][k+1], b1 = Bs[k+1][tx];
        sr1 = fmaf(a1.x, b1.x, sr1); sr1 = fmaf(-a1.y, b1.y, sr1);
        si1 = fmaf(a1.x, b1.y, si1); si1 = fmaf(a1.y, b1.x, si1);
    }
    float sr = sr0 + sr1, si = si0 + si1;
    if (tz > 0) Rs[tz-1][ty][tx] = make_float2(sr, si);
    __syncthreads();
    if (tz == 0) {
        sr += Rs[0][ty][tx].x + Rs[1][ty][tx].x + Rs[2][ty][tx].x;
        si += Rs[0][ty][tx].y + Rs[1][ty][tx].y + Rs[2][ty][tx].y;
        int d = r0 + ty, e = c0 + tx;
        if (mode == 0)      M2c[d*NDIM + e] = make_float2(sr, si);
        else if (mode == 1) M3c[d*NDIM + e] = make_float2(sr, si);
        else {
            int g = d * NDIM + e;
            float ur = sr + ((d == e) ? 1.f : 0.f) + H[NN + g] + M2c[g].x * 0.5f;
            Ut[e * NDIM + d] = f2bf(ur);         // transposed: Ut[col][k]
        }
    }
}

// ---------------- main GEMM: out[131072 x 256] = psi @ Re(U) ----------------
// HYBRID (best of R5-7 + R8-9): mfma_32x32x16 (2x FLOP per B-byte), B staged
// in 64 KB LDS (this block's 128-col half of Ut, XOR-swizzled, conflict-free),
// C stored DIRECTLY from acc regs (32x32 layout: one 4B/lane store = 2 full
// 128B lines -> no epilogue, no transpose, no write amp). 512 thr = 8 waves
// x 32-row strips; grid 1024 (512 row-groups x 2 col-halves). VGPR by design
// ~120 (acc 64 + A-ring 24 + transients) -> launch_bounds(512,4) = 128 cap,
// 2 blocks/CU = 16 waves/CU TLP. A streams via depth-3 ring.
__global__ __launch_bounds__(512, 4) void kgemm(
    const float* __restrict__ psi, const unsigned short* __restrict__ Ut,
    float* __restrict__ out) {
    __shared__ unsigned short Bls[128 * NDIM];  // 64 KB
    const int t = threadIdx.x;
    const int colh = blockIdx.x & 1;            // which 128-col half of U
    const int grp  = blockIdx.x >> 1;           // 256-row group

    // stage Ut[colh*128 ..][*] -> LDS: 16B chunk (col cl, slot j) at
    // (cl<<5)|(j^(cl&7))  [R5-7-proven swizzle, conflict-free]
    const s8bf* Ug = (const s8bf*)(Ut + (size_t)colh * 128 * NDIM);
    s8bf* Bg = (s8bf*)Bls;
#pragma unroll
    for (int i = 0; i < 8; ++i) {
        int g = i * 512 + t;                    // [0, 4096)
        int cl = g >> 5, j = g & 31;
        Bg[(cl << 5) | (j ^ (cl & 7))] = Ug[g];
    }
    __syncthreads();

    const int w = t >> 6, l = t & 63;
    const int lr = l & 31, half = l >> 5;
    const size_t r0 = (size_t)grp * 256 + w * 32;       // wave's 32 rows

    const f32x4* psi4 = (const f32x4*)psi;
    const size_t abase = (r0 + lr) * 64 + half * 2;     // f32x4 units

    f32x4 Ar[3][2];                              // depth-3 k-step ring
#pragma unroll
    for (int p = 0; p < 3; ++p) {
        Ar[p][0] = psi4[abase + p * 4];
        Ar[p][1] = psi4[abase + p * 4 + 1];
    }

    f32x16 acc[4];
#pragma unroll
    for (int p = 0; p < 4; ++p) acc[p] = (f32x16)0.f;

#pragma unroll
    for (int ks = 0; ks < 16; ++ks) {            // K = 16 per step
        s8bf a;                                  // A: row=lr, k=ks*16+half*8+j
#pragma unroll
        for (int j = 0; j < 4; ++j) {
            a[j]     = f2bfs(Ar[ks % 3][0][j]);
            a[j + 4] = f2bfs(Ar[ks % 3][1][j]);
        }
        if (ks + 3 < 16) {                       // refill ring slot for ks+3
            Ar[ks % 3][0] = psi4[abase + (ks + 3) * 4];
            Ar[ks % 3][1] = psi4[abase + (ks + 3) * 4 + 1];
        }
        const int slot = 2 * ks + half;
#pragma unroll
        for (int p = 0; p < 4; ++p) {            // 4 col-panels of 32
            int cl = p * 32 + lr;
            s8bf bb = Bg[(cl << 5) | (slot ^ (cl & 7))];
            acc[p] = __builtin_amdgcn_mfma_f32_32x32x16_bf16(a, bb, acc[p], 0, 0, 0);
        }
    }

    // direct C stores: col=lane&31, row=(r&3)+8*(r>>2)+4*half [m74/m101,
    // R8/9-verified]. Each instr = 2 full 128B lines, NT, no RMW.
    const int colb = colh * 128;
#pragma unroll
    for (int p = 0; p < 4; ++p) {
#pragma unroll
        for (int r = 0; r < 16; ++r) {
            size_t row = r0 + (r & 3) + 8 * (r >> 2) + 4 * half;
            __builtin_nontemporal_store(acc[p][r], &out[row * NDIM + colb + p * 32 + lr]);
        }
    }
}

extern "C" void kernel_launch(void* const* d_in, const int* in_sizes, int n_in,
                              void* d_out, int out_size, void* d_ws, size_t ws_size,
                              hipStream_t stream) {
    const float* psi = (const float*)d_in[0];   // [8,4096,4,256] f32
    const float* H   = (const float*)d_in[1];   // [4,256,256]    f32
    float* out = (float*)d_out;                 // [8,4096,4,256] f32

    float2* M2c = (float2*)d_ws;                // NN complex
    float2* M3c = M2c + NN;                     // NN complex
    unsigned short* Ut = (unsigned short*)(M3c + NN);  // NN bf16 (Ut[col][k])

    dim3 cb(16, 16, 4), cg(16, 16);
    kmm<<<cg, cb, 0, stream>>>(H, M2c, M3c, Ut, 0);   // M2 = M*M
    kmm<<<cg, cb, 0, stream>>>(H, M2c, M3c, Ut, 1);   // M3 = M2*M
    kmm<<<cg, cb, 0, stream>>>(H, M2c, M3c, Ut, 2);   // Ut = bf16(Re(U))^T
    kgemm<<<1024, 512, 0, stream>>>(psi, Ut, out);
}

// Round 11
// 78.388 us; speedup vs baseline: 1.4886x; 1.1492x over previous
//
#include <hip/hip_runtime.h>
#include <hip/hip_bf16.h>

#define NDIM 256
#define NN (NDIM*NDIM)

typedef __attribute__((ext_vector_type(8))) short s8bf;     // 8 x bf16 (4 VGPRs)
typedef __attribute__((ext_vector_type(4))) float f32x4;    // native float4
typedef __attribute__((ext_vector_type(16))) float f32x16;  // 32x32 MFMA accum

__device__ __forceinline__ unsigned short f2bf(float f) {
    union { float f; unsigned u; } v; v.f = f;
    unsigned u = v.u;
    return (unsigned short)((u + 0x7FFFu + ((u >> 16) & 1u)) >> 16);  // RNE
}
__device__ __forceinline__ short f2bfs(float f) {           // compiler emits v_cvt_pk_bf16_f32
    __hip_bfloat16 h = __float2bfloat16(f);
    union { __hip_bfloat16 h; short s; } v; v.h = h;
    return v.s;
}

#define AS1 __attribute__((address_space(1)))
#define AS3 __attribute__((address_space(3)))
__device__ __forceinline__ void gl_lds16(const void* g, void* l) {
    // async global->LDS DMA, 16B/lane; dest must be linear in lane order
    __builtin_amdgcn_global_load_lds((const AS1 unsigned int*)g,
                                     (AS3 unsigned int*)l, 16, 0, 0);
}

// ---------------- expm pipeline: U = B0 + M3*(B1 + M3/720) ----------------
// M = H1 - i*H0. deg-6 Taylor; truncation ~1e-4 << bf16 noise.
__global__ __launch_bounds__(1024) void kmm(
    const float* __restrict__ H, float2* __restrict__ M2c, float2* __restrict__ M3c,
    unsigned short* __restrict__ Ut, int mode) {
    __shared__ float2 As[16][257];
    __shared__ float2 Bs[256][17];
    __shared__ float2 Rs[3][16][17];
    const int tx = threadIdx.x, ty = threadIdx.y, tz = threadIdx.z;
    const int tid = (tz * 16 + ty) * 16 + tx;
    const int r0 = blockIdx.y * 16, c0 = blockIdx.x * 16;

#pragma unroll
    for (int i = 0; i < 4; ++i) {               // A panel: 16 rows x 256 k
        int idx = i * 1024 + tid;
        int r = idx >> 8, k = idx & 255;
        float2 a;
        if (mode == 0)      { a.x = H[NN + (r0+r)*NDIM + k]; a.y = -H[(r0+r)*NDIM + k]; }
        else if (mode == 1) a = M2c[(r0+r)*NDIM + k];
        else                a = M3c[(r0+r)*NDIM + k];
        As[r][k] = a;
    }
#pragma unroll
    for (int i = 0; i < 4; ++i) {               // B panel: 256 k x 16 cols
        int idx = i * 1024 + tid;
        int k = idx >> 4, cc = idx & 15;
        float2 b;
        if (mode <= 1) { b.x = H[NN + k*NDIM + c0+cc]; b.y = -H[k*NDIM + c0+cc]; }
        else {
            int g = k * NDIM + c0 + cc;
            float mr = H[NN + g], mi = -H[g];
            float2 m2 = M2c[g], m3 = M3c[g];
            float di = (k == c0 + cc) ? 1.f : 0.f;
            b.x = di*(1.f/6.f) + mr*(1.f/24.f) + m2.x*(1.f/120.f) + m3.x*(1.f/720.f);
            b.y =                mi*(1.f/24.f) + m2.y*(1.f/120.f) + m3.y*(1.f/720.f);
        }
        Bs[k][cc] = b;
    }
    __syncthreads();

    float sr0=0.f, si0=0.f, sr1=0.f, si1=0.f;
#pragma unroll 8
    for (int k = tz*64; k < tz*64 + 64; k += 2) {
        float2 a = As[ty][k], b = Bs[k][tx];
        sr0 = fmaf(a.x, b.x, sr0); sr0 = fmaf(-a.y, b.y, sr0);
        si0 = fmaf(a.x, b.y, si0); si0 = fmaf(a.y, b.x, si0);
        float2 a1 = As[ty][k+1], b1 = Bs[k+1][tx];
        sr1 = fmaf(a1.x, b1.x, sr1); sr1 = fmaf(-a1.y, b1.y, sr1);
        si1 = fmaf(a1.x, b1.y, si1); si1 = fmaf(a1.y, b1.x, si1);
    }
    float sr = sr0 + sr1, si = si0 + si1;
    if (tz > 0) Rs[tz-1][ty][tx] = make_float2(sr, si);
    __syncthreads();
    if (tz == 0) {
        sr += Rs[0][ty][tx].x + Rs[1][ty][tx].x + Rs[2][ty][tx].x;
        si += Rs[0][ty][tx].y + Rs[1][ty][tx].y + Rs[2][ty][tx].y;
        int d = r0 + ty, e = c0 + tx;
        if (mode == 0)      M2c[d*NDIM + e] = make_float2(sr, si);
        else if (mode == 1) M3c[d*NDIM + e] = make_float2(sr, si);
        else {
            int g = d * NDIM + e;
            float ur = sr + ((d == e) ? 1.f : 0.f) + H[NN + g] + M2c[g].x * 0.5f;
            Ut[e * NDIM + d] = f2bf(ur);         // transposed: Ut[col][k]
        }
    }
}

// ---------------- main GEMM: out[131072 x 256] = psi @ Re(U) ----------------
// T3/T4 structure: psi staged via global_load_lds into a 4-slot x 8 KB LDS
// ring with COUNTED vmcnt (3 slices = 24 KB/CU permanently in flight; never
// drains to 0) -> BW-paced, not latency-paced. B = full Ut in 128 KB LDS
// (loaded once, pre-swizzled SOURCE + linear DMA dest, rule 21). 1024 thr =
// 16 waves = 2 rowgroups x 8 col-panels; mfma_32x32x16; C stored directly
// from acc (full-line 32x32 layout, R10-verified). Raw s_barrier (no vmcnt
// drain) + sched_barrier(0) pins. Grid 256 = 1 block/CU, psi read ONCE.
__global__ __launch_bounds__(1024, 4) void kgemm(
    const float* __restrict__ psi, const unsigned short* __restrict__ Ut,
    float* __restrict__ out) {
    __shared__ unsigned short Bls[NN];        // 128 KB
    __shared__ float Apsi[4][2048];           // 4 x 8 KB psi ring -> 160 KiB total
    const int t = threadIdx.x;
    const int w = t >> 6, l = t & 63;
    const int lr = l & 31, half = l >> 5;
    const int wr = w >> 3, p8 = w & 7;
    const size_t row0 = (size_t)blockIdx.x * 512;

    // ---- prologue: stage B. LDS(cl,j) <- Ut chunk (cl, j^(cl&7)) ----
    const char* Utb = (const char*)Ut;
#pragma unroll
    for (int i = 0; i < 8; ++i) {
        int g = i * 1024 + t;                 // 16B chunk id [0, 8192)
        int cl = g >> 5, j = g & 31;
        gl_lds16(Utb + (((size_t)cl << 5) | (j ^ (cl & 7))) * 16,
                 (char*)Bls + (size_t)g * 16);
    }
    // ---- prologue: psi slices 0..3 (threads 0..511, 1 DMA each/slice) ----
    const int sr = t >> 3, sc = t & 7;        // staged row 0..63, chunk 0..7
    const int scs = sc ^ (sr & 7);            // pre-swizzled source chunk
    if (w < 8) {
#pragma unroll
        for (int s = 0; s < 4; ++s)
            gl_lds16(psi + (row0 + sr) * NDIM + s * 32 + scs * 4, &Apsi[s][t * 4]);
        asm volatile("s_waitcnt vmcnt(3)" ::: "memory");   // B + slice0 done
    } else {
        asm volatile("s_waitcnt vmcnt(0)" ::: "memory");   // own B chunks done
    }
    __builtin_amdgcn_s_barrier();
    __builtin_amdgcn_sched_barrier(0);

    const int clB = p8 * 32 + lr;             // this lane's B column
    const int clK = clB & 7;                  // B swizzle key
    const int rA = wr * 32 + lr;              // this lane's A row in strip
    const int rK = rA & 7;                    // A swizzle key
    f32x16 acc = (f32x16)0.f;

#pragma unroll 1
    for (int strip = 0; strip < 8; ++strip) {
        const size_t rowg = row0 + strip * 64 + wr * 32;
#pragma unroll
        for (int sl = 0; sl < 8; ++sl) {
            const int sg = strip * 8 + sl;
            const float* Ap = &Apsi[sl & 3][0];
            // ---- compute: 2 MFMAs (k = sl*32 .. +32) ----
#pragma unroll
            for (int X = 0; X < 2; ++X) {
                const int cq = 4 * X + 2 * half;
                f32x4 a0 = *(const f32x4*)(Ap + rA * 32 + ((cq    ) ^ rK) * 4);
                f32x4 a1 = *(const f32x4*)(Ap + rA * 32 + ((cq + 1) ^ rK) * 4);
                s8bf a;
#pragma unroll
                for (int j = 0; j < 4; ++j) {
                    a[j]     = f2bfs(a0[j]);
                    a[j + 4] = f2bfs(a1[j]);
                }
                const int jp = sl * 4 + 2 * X + half;
                s8bf bb = *(const s8bf*)(Bls + (size_t)(((clB << 5) | (jp ^ clK)) << 3));
                acc = __builtin_amdgcn_mfma_f32_32x32x16_bf16(a, bb, acc, 0, 0, 0);
            }
            if (sl == 7) {                    // strip done: direct full-line stores
#pragma unroll
                for (int r = 0; r < 16; ++r) {
                    size_t row = rowg + (r & 3) + 8 * (r >> 2) + 4 * half;
                    __builtin_nontemporal_store(acc[r], &out[row * NDIM + clB]);
                }
                acc = (f32x16)0.f;
            }
            __builtin_amdgcn_s_barrier();     // all waves done reading slot sl&3
            __builtin_amdgcn_sched_barrier(0);
            if (w < 8) {                      // refill slot with slice sg+4
                int sgn = sg + 4;
                int sgc = sgn < 64 ? sgn : 63;            // tail: dup of last slice
                gl_lds16(psi + (row0 + (sgc >> 3) * 64 + sr) * NDIM
                             + (sgc & 7) * 32 + scs * 4,
                         &Apsi[sl & 3][t * 4]);
                // counted wait: slice sg+1 (oldest DMA) arrived; 3 stay in flight.
                // strip-end: +16 outstanding C-stores precede the newest DMA.
                if (sl == 7) asm volatile("s_waitcnt vmcnt(19)" ::: "memory");
                else         asm volatile("s_waitcnt vmcnt(3)"  ::: "memory");
            }
            __builtin_amdgcn_s_barrier();     // publish slice sg+1
            __builtin_amdgcn_sched_barrier(0);
        }
    }
}

extern "C" void kernel_launch(void* const* d_in, const int* in_sizes, int n_in,
                              void* d_out, int out_size, void* d_ws, size_t ws_size,
                              hipStream_t stream) {
    const float* psi = (const float*)d_in[0];   // [8,4096,4,256] f32
    const float* H   = (const float*)d_in[1];   // [4,256,256]    f32
    float* out = (float*)d_out;                 // [8,4096,4,256] f32

    float2* M2c = (float2*)d_ws;                // NN complex
    float2* M3c = M2c + NN;                     // NN complex
    unsigned short* Ut = (unsigned short*)(M3c + NN);  // NN bf16 (Ut[col][k])

    dim3 cb(16, 16, 4), cg(16, 16);
    kmm<<<cg, cb, 0, stream>>>(H, M2c, M3c, Ut, 0);   // M2 = M*M
    kmm<<<cg, cb, 0, stream>>>(H, M2c, M3c, Ut, 1);   // M3 = M2*M
    kmm<<<cg, cb, 0, stream>>>(H, M2c, M3c, Ut, 2);   // Ut = bf16(Re(U))^T
    kgemm<<<256, 1024, 0, stream>>>(psi, Ut, out);
}